// Round 12
// baseline (251.492 us; speedup 1.0000x reference)
//
#include <hip/hip_runtime.h>

// PsRoiOffset, round 11: wave-per-site + COALESCED B fragments.
// features (1,200,304,196) f32, rois (512,4) f32,
// W_off (3,3,196,392) f32, b_off (392) f32, out (512,7,7,4) f32.
//
// ws: bf16 feature map [H][W][224] (K-padded)  +  bf16 weight fragments
// packed in exact MFMA-lane order [49][9][7][64 lanes][8 bf16] -- one
// B-fragment load = 1KB contiguous (coalesced, 16 sequential lines)
// instead of 8 scattered lines. A-fragments load directly from the map.
// One wave per (roi,bin) site, no LDS, no barriers; C redistribution and
// the PS-ROI combine are pure wave shuffles.

constexpr int H = 200, W = 304, C = 196, CO = 392;
constexpr int KK = 7, DIM = 4, NROI = 512;
constexpr int KW = 224;                       // padded K (feature map)
constexpr int KP = 232;                       // fallback LDS A row stride
constexpr size_t F_ELEMS = (size_t)H * W * KW;              // bf16
constexpr size_t WPK_ELEMS = (size_t)49 * 9 * 7 * 64 * 8;   // bf16 frags
constexpr size_t WS_NEED = (F_ELEMS + WPK_ELEMS) * 2;       // ~30.4 MB

typedef __attribute__((ext_vector_type(8))) short bf16x8;
typedef __attribute__((ext_vector_type(4))) float f32x4;

static __device__ inline unsigned short f2bf(float x) {
  unsigned int u = __float_as_uint(x);
  return (unsigned short)((u + 0x7FFFu + ((u >> 16) & 1u)) >> 16);
}

static __device__ inline void roi_geom(const float* __restrict__ rois, int n,
                                       int bi, int bj,
                                       int* ycand, int* xcand,
                                       float* wy, float* wx) {
  const float rx1 = rois[n * 4 + 0] * 0.25f;
  const float ry1 = rois[n * 4 + 1] * 0.25f;
  const float rx2 = rois[n * 4 + 2] * 0.25f;
  const float ry2 = rois[n * 4 + 3] * 0.25f;
  const float bh = (ry2 - ry1) * (1.0f / 7.0f);
  const float bw = (rx2 - rx1) * (1.0f / 7.0f);
#pragma unroll
  for (int si = 0; si < 2; ++si) {
    float sy = ry1 + ((float)bi + ((float)si + 0.5f) * 0.5f) * bh;
    sy = fminf(fmaxf(sy, 0.0f), (float)(H - 1));
    float fy = floorf(sy);
    wy[si] = sy - fy;
    int i0 = (int)fy;
    ycand[2 * si] = i0;
    ycand[2 * si + 1] = min(i0 + 1, H - 1);

    float sx = rx1 + ((float)bj + ((float)si + 0.5f) * 0.5f) * bw;
    sx = fminf(fmaxf(sx, 0.0f), (float)(W - 1));
    float fx = floorf(sx);
    wx[si] = sx - fx;
    int j0 = (int)fx;
    xcand[2 * si] = j0;
    xcand[2 * si + 1] = min(j0 + 1, W - 1);
  }
}

// ---- fused prep: features -> bf16 map  AND  weights -> packed fragments ----
// blocks [0, FBLK): feature convert; blocks [FBLK, FBLK+WBLK): weight pack.
constexpr long long FTOT = (long long)H * W * (KW / 4);      // ushort4 units
constexpr int FBLK = (int)((FTOT + 255) / 256);
constexpr int WTOT = 49 * 9 * 7 * 64;                        // frag-slots
constexpr int WBLK = (WTOT + 255) / 256;

__global__ __launch_bounds__(256) void prep_kernel(
    const float* __restrict__ feat, const float* __restrict__ Woff,
    unsigned short* __restrict__ fbf, unsigned short* __restrict__ wpk)
{
  const int b = blockIdx.x;
  if (b < FBLK) {
    const long long u = (long long)b * 256 + threadIdx.x;
    if (u >= FTOT) return;
    const int k4 = (int)(u % (KW / 4));
    const long long pix = u / (KW / 4);
    const int k = k4 * 4;
    ushort4 v = make_ushort4(0, 0, 0, 0);
    const float* src = feat + pix * C;
#pragma unroll
    for (int j = 0; j < 4; ++j)
      if (k + j < C) ((unsigned short*)&v)[j] = f2bf(src[k + j]);
    *reinterpret_cast<ushort4*>(fbf + pix * KW + k) = v;
  } else {
    const int u = (b - FBLK) * 256 + threadIdx.x;   // frag-slot id
    if (u >= WTOT) return;
    const int lane = u & 63;
    const int ks = (u >> 6) % 7;
    const int p  = (u / (64 * 7)) % 9;
    const int g  = u / (64 * 7 * 9);
    const int m_lane = lane & 15, k_hi = lane >> 4;
    unsigned short vv[8];
#pragma unroll
    for (int j = 0; j < 8; ++j) vv[j] = 0;
    if (m_lane < 8) {
      const int o = g * 8 + m_lane;
#pragma unroll
      for (int j = 0; j < 8; ++j) {
        const int k = ks * 32 + k_hi * 8 + j;
        if (k < C) vv[j] = f2bf(Woff[(size_t)(p * C + k) * CO + o]);
      }
    }
    ushort4 lo = make_ushort4(vv[0], vv[1], vv[2], vv[3]);
    ushort4 hi = make_ushort4(vv[4], vv[5], vv[6], vv[7]);
    unsigned short* dst = wpk + (size_t)u * 8;
    *reinterpret_cast<ushort4*>(dst) = lo;
    *reinterpret_cast<ushort4*>(dst + 4) = hi;
  }
}

// ---- main: one wave per (roi, bin); no LDS, no barriers ----
__global__ __launch_bounds__(256) void psroi_wave_kernel(
    const float* __restrict__ feat, const float* __restrict__ rois,
    const unsigned short* __restrict__ fbf,
    const unsigned short* __restrict__ wpk,
    const float* __restrict__ boff, float* __restrict__ out)
{
  // bijective XCD swizzle over 6272 blocks (6272 % 8 == 0)
  const int bid = blockIdx.x;
  const int wid = (bid & 7) * (49 * NROI / 4 / 8) + (bid >> 3);
  const int wv = threadIdx.x >> 6;
  const int lane = threadIdx.x & 63;
  const int site = wid * 4 + wv;            // 0..25087
  const int n = site / 49, g = site % 49;
  const int bi = g / KK, bj = g % KK;
  const int m_lane = lane & 15;
  const int k_hi = lane >> 4;

  int yc4[4], xc4[4];
  float wy2[2], wx2[2];
  roi_geom(rois, n, bi, bj, yc4, xc4, wy2, wx2);

  // this lane's corner for A rows (corner id = m_lane = ycidx*4 + xcidx)
  const int ycc = yc4[m_lane >> 2];
  const int xcc = xc4[m_lane & 3];

  f32x4 acc = {0.f, 0.f, 0.f, 0.f};
  // packed B base for this bin; per (p,ks) fragment at + (p*7+ks)*512 + lane*8
  const unsigned short* wg = wpk + (size_t)g * 9 * 7 * 64 * 8 + lane * 8;

  // ---- conv: 3 dy-strips x (7 ks x 3 dx) fully unrolled per strip ----
#pragma unroll 1
  for (int dy = -1; dy <= 1; ++dy) {
    const int ys = ycc + dy;
    const bool yok = (ys >= 0) && (ys < H);
    bool aok[3];
    const unsigned short* ar[3];
    const unsigned short* br[3];
#pragma unroll
    for (int t = 0; t < 3; ++t) {
      const int xs = xcc + t - 1;
      aok[t] = yok && (xs >= 0) && (xs < W);
      ar[t] = fbf + (size_t)(ys * W + xs) * KW + k_hi * 8;
      const int p = (dy + 1) * 3 + t;
      br[t] = wg + (size_t)(p * 7) * 512;
    }
#pragma unroll
    for (int ks = 0; ks < 7; ++ks) {
#pragma unroll
      for (int t = 0; t < 3; ++t) {
        bf16x8 a = (bf16x8)(short)0;
        if (aok[t]) a = *reinterpret_cast<const bf16x8*>(ar[t] + ks * 32);
        const bf16x8 b = *reinterpret_cast<const bf16x8*>(br[t] + ks * 512);
        acc = __builtin_amdgcn_mfma_f32_16x16x32_bf16(a, b, acc, 0, 0, 0);
      }
    }
  }

  // ---- C redistribution via shuffles (no LDS, no barrier) ----
  const int ct = lane >> 2;                 // target corner 0..15
  const int d  = lane & 3;
  const int srcy = ((ct >> 2) << 4) + 2 * d;
  const int srcx = srcy + 1;
  const float ty0 = __shfl(acc[0], srcy), ty1 = __shfl(acc[1], srcy);
  const float ty2 = __shfl(acc[2], srcy), ty3 = __shfl(acc[3], srcy);
  const float tx0 = __shfl(acc[0], srcx), tx1 = __shfl(acc[1], srcx);
  const float tx2 = __shfl(acc[2], srcx), tx3 = __shfl(acc[3], srcx);
  const int rr = ct & 3;
  float offy = (rr == 0) ? ty0 : (rr == 1) ? ty1 : (rr == 2) ? ty2 : ty3;
  float offx = (rr == 0) ? tx0 : (rr == 1) ? tx1 : (rr == 2) ? tx2 : tx3;

  // ---- deformable bilinear fetch (fp32 features) + PS-ROI combine ----
  const int c = g * DIM + d;
  offy += boff[2 * c];
  offx += boff[2 * c + 1];
  const int yc = yc4[ct >> 2];
  const int xc = xc4[ct & 3];

  float yy = fminf(fmaxf((float)yc + offy, 0.0f), (float)(H - 1));
  float xx = fminf(fmaxf((float)xc + offx, 0.0f), (float)(W - 1));
  const float fy = floorf(yy), fx = floorf(xx);
  const float ay = yy - fy, ax = xx - fx;
  const int iy0 = (int)fy, ix0 = (int)fx;
  const int iy1 = min(iy0 + 1, H - 1), ix1 = min(ix0 + 1, W - 1);
  const float v00 = feat[(size_t)(iy0 * W + ix0) * C + c];
  const float v01 = feat[(size_t)(iy0 * W + ix1) * C + c];
  const float v10 = feat[(size_t)(iy1 * W + ix0) * C + c];
  const float v11 = feat[(size_t)(iy1 * W + ix1) * C + c];
  const float top = v00 + (v01 - v00) * ax;
  const float bot = v10 + (v11 - v10) * ax;
  const float om = top + (bot - top) * ay;

  const int yci = ct >> 2, xci = ct & 3;
  const int si = yci >> 1, a = yci & 1;
  const int sj = xci >> 1, b = xci & 1;
  const float cy = a ? wy2[si] : 1.0f - wy2[si];
  const float cx = b ? wx2[sj] : 1.0f - wx2[sj];
  float v = 0.25f * cy * cx * om;

  v += __shfl_xor(v, 4);
  v += __shfl_xor(v, 8);
  v += __shfl_xor(v, 16);
  v += __shfl_xor(v, 32);

  if (lane < 4)
    out[(size_t)n * (KK * KK * DIM) + g * DIM + lane] = v;
}

// ---- fallback (ws too small): round-6 union kernel, fp32 inputs ----
__global__ __launch_bounds__(256) void psroi_union_kernel(
    const float* __restrict__ feat, const float* __restrict__ rois,
    const float* __restrict__ Woff, const float* __restrict__ boff,
    float* __restrict__ out)
{
  const int bid = blockIdx.x;
  const int wid = (bid & 7) * (49 * NROI / 8) + (bid >> 3);
  const int g = wid % 49;
  const int n = wid / 49;
  const int bi = g / KK, bj = g % KK;
  const int tid = threadIdx.x;
  const int lane = tid & 63;
  const int wv = tid >> 6;
  const int m_lane = lane & 15;
  const int k_hi = lane >> 4;

  __shared__ short Abuf[64 * KP];
  __shared__ float Cbuf[4 * 16 * 9];

  for (int i = tid; i < 64 * (KP - C); i += 256) {
    const int row = i / (KP - C), col = C + i % (KP - C);
    Abuf[row * KP + col] = 0;
  }

  int yc4[4], xc4[4];
  float wy2[2], wx2[2];
  roi_geom(rois, n, bi, bj, yc4, xc4, wy2, wx2);

  {
    const int pos = tid >> 2;
    const int yi = pos >> 3, xi = pos & 7;
    const int yrow = (yi < 4) ? (yc4[0] + yi - 1) : (yc4[2] + yi - 5);
    const int xcol = (xi < 4) ? (xc4[0] + xi - 1) : (xc4[2] + xi - 5);
    const bool valid = (yrow >= 0) && (yrow < H) && (xcol >= 0) && (xcol < W);
    const float* frow = feat + (size_t)(yrow * W + xcol) * C;
    short* arow = &Abuf[pos * KP];
    const int l = tid & 3;
#pragma unroll
    for (int k = 0; k <= 12; ++k) {
      const int c = l + 4 * k;
      if (c < 49) {
        ushort4 v = make_ushort4(0, 0, 0, 0);
        if (valid) {
          const float4 f4 = *reinterpret_cast<const float4*>(frow + 4 * c);
          v.x = f2bf(f4.x); v.y = f2bf(f4.y);
          v.z = f2bf(f4.z); v.w = f2bf(f4.w);
        }
        *reinterpret_cast<ushort4*>(arow + 4 * c) = v;
      }
    }
  }
  __syncthreads();

  const int i0 = m_lane >> 2, j0 = m_lane & 3;
  const int dyA = yc4[1] - yc4[0], dyB = yc4[3] - yc4[2];
  const int dxA = xc4[1] - xc4[0], dxB = xc4[3] - xc4[2];
  int ybase = (i0 & 2) ? 5 : 1;
  ybase += (i0 & 1) ? ((i0 & 2) ? dyB : dyA) : 0;
  int xbase = (j0 & 2) ? 5 : 1;
  xbase += (j0 & 1) ? ((j0 & 2) ? dxB : dxA) : 0;

  f32x4 acc = {0.f, 0.f, 0.f, 0.f};

#pragma unroll 1
  for (int p = wv; p < 9; p += 4) {
    bf16x8 bfr[7];
#pragma unroll
    for (int ks = 0; ks < 7; ++ks) bfr[ks] = (bf16x8)(short)0;
    if (m_lane < 8) {
#pragma unroll
      for (int ks = 0; ks < 7; ++ks) {
        bf16x8 b = (bf16x8)(short)0;
#pragma unroll
        for (int j = 0; j < 8; ++j) {
          const int k = ks * 32 + k_hi * 8 + j;
          if (k < C)
            b[j] = (short)f2bf(Woff[(size_t)(p * C + k) * CO + g * 8 + m_lane]);
        }
        bfr[ks] = b;
      }
    }
    const int row = (ybase + p / 3 - 1) * 8 + (xbase + p % 3 - 1);
    const short* arow = &Abuf[row * KP];
#pragma unroll
    for (int ks = 0; ks < 7; ++ks) {
      const bf16x8 a = *reinterpret_cast<const bf16x8*>(arow + ks * 32 + k_hi * 8);
      acc = __builtin_amdgcn_mfma_f32_16x16x32_bf16(a, bfr[ks], acc, 0, 0, 0);
    }
  }

  if (m_lane < 8) {
#pragma unroll
    for (int r = 0; r < 4; ++r)
      Cbuf[(wv * 16 + k_hi * 4 + r) * 9 + m_lane] = acc[r];
  }
  __syncthreads();

  if (tid < 64) {
    const int corner = tid >> 2;
    const int d = tid & 3;
    const int yc = yc4[corner >> 2];
    const int xc = xc4[corner & 3];
    const int c = g * DIM + d;

    float offy = boff[2 * c], offx = boff[2 * c + 1];
#pragma unroll
    for (int w = 0; w < 4; ++w) {
      offy += Cbuf[(w * 16 + corner) * 9 + 2 * d];
      offx += Cbuf[(w * 16 + corner) * 9 + 2 * d + 1];
    }

    float yy = fminf(fmaxf((float)yc + offy, 0.0f), (float)(H - 1));
    float xx = fminf(fmaxf((float)xc + offx, 0.0f), (float)(W - 1));
    const float fy = floorf(yy), fx = floorf(xx);
    const float ay = yy - fy, ax = xx - fx;
    const int iy0 = (int)fy, ix0 = (int)fx;
    const int iy1 = min(iy0 + 1, H - 1), ix1 = min(ix0 + 1, W - 1);
    const float v00 = feat[(size_t)(iy0 * W + ix0) * C + c];
    const float v01 = feat[(size_t)(iy0 * W + ix1) * C + c];
    const float v10 = feat[(size_t)(iy1 * W + ix0) * C + c];
    const float v11 = feat[(size_t)(iy1 * W + ix1) * C + c];
    const float top = v00 + (v01 - v00) * ax;
    const float bot = v10 + (v11 - v10) * ax;
    const float om = top + (bot - top) * ay;

    const int yci = corner >> 2, xci = corner & 3;
    const int si = yci >> 1, a = yci & 1;
    const int sj = xci >> 1, b = xci & 1;
    const float cy = a ? wy2[si] : 1.0f - wy2[si];
    const float cx = b ? wx2[sj] : 1.0f - wx2[sj];
    float v = 0.25f * cy * cx * om;

    v += __shfl_xor(v, 4);
    v += __shfl_xor(v, 8);
    v += __shfl_xor(v, 16);
    v += __shfl_xor(v, 32);

    if (tid < 4)
      out[(size_t)n * (KK * KK * DIM) + g * DIM + tid] = v;
  }
}

extern "C" void kernel_launch(void* const* d_in, const int* in_sizes, int n_in,
                              void* d_out, int out_size, void* d_ws, size_t ws_size,
                              hipStream_t stream) {
  const float* feat = (const float*)d_in[0];
  const float* rois = (const float*)d_in[1];
  const float* Woff = (const float*)d_in[2];
  const float* boff = (const float*)d_in[3];
  float* out = (float*)d_out;

  if (ws_size >= WS_NEED) {
    unsigned short* fbf = (unsigned short*)d_ws;
    unsigned short* wpk = fbf + F_ELEMS;
    prep_kernel<<<dim3(FBLK + WBLK), dim3(256), 0, stream>>>(feat, Woff, fbf, wpk);
    psroi_wave_kernel<<<dim3(49 * NROI / 4), dim3(256), 0, stream>>>(
        feat, rois, fbf, wpk, boff, out);
  } else {
    psroi_union_kernel<<<dim3(49 * NROI), dim3(256), 0, stream>>>(
        feat, rois, Woff, boff, out);
  }
}

// Round 13
// 239.360 us; speedup vs baseline: 1.0507x; 1.0507x over previous
//
#include <hip/hip_runtime.h>

// PsRoiOffset, round 12: wave-per-site (R10 structure, scattered-B) with
// FULL unroll of all 9 taps + __launch_bounds__(256,4) so the compiler
// has a 128-VGPR budget to hoist loads (R10 sat at VGPR=28 -> only ~4
// loads in flight -> vmcnt-serialized inner loop).
//
// features (1,200,304,196) f32, rois (512,4) f32,
// W_off (3,3,196,392) f32, b_off (392) f32, out (512,7,7,4) f32.
//
// ws: bf16 feature map [H][W][224] (K-padded) + bf16 weights [49][9][8][224].

constexpr int H = 200, W = 304, C = 196, CO = 392;
constexpr int KK = 7, DIM = 4, NROI = 512;
constexpr int KW = 224;                       // padded K (map + weights)
constexpr int KP = 232;                       // fallback LDS A row stride
constexpr size_t F_ELEMS = (size_t)H * W * KW;
constexpr size_t W_ELEMS = (size_t)49 * 9 * 8 * KW;
constexpr size_t WS_NEED = (F_ELEMS + W_ELEMS) * 2;   // ~28.8 MB

typedef __attribute__((ext_vector_type(8))) short bf16x8;
typedef __attribute__((ext_vector_type(4))) float f32x4;

static __device__ inline unsigned short f2bf(float x) {
  unsigned int u = __float_as_uint(x);
  return (unsigned short)((u + 0x7FFFu + ((u >> 16) & 1u)) >> 16);
}

static __device__ inline void roi_geom(const float* __restrict__ rois, int n,
                                       int bi, int bj,
                                       int* ycand, int* xcand,
                                       float* wy, float* wx) {
  const float rx1 = rois[n * 4 + 0] * 0.25f;
  const float ry1 = rois[n * 4 + 1] * 0.25f;
  const float rx2 = rois[n * 4 + 2] * 0.25f;
  const float ry2 = rois[n * 4 + 3] * 0.25f;
  const float bh = (ry2 - ry1) * (1.0f / 7.0f);
  const float bw = (rx2 - rx1) * (1.0f / 7.0f);
#pragma unroll
  for (int si = 0; si < 2; ++si) {
    float sy = ry1 + ((float)bi + ((float)si + 0.5f) * 0.5f) * bh;
    sy = fminf(fmaxf(sy, 0.0f), (float)(H - 1));
    float fy = floorf(sy);
    wy[si] = sy - fy;
    int i0 = (int)fy;
    ycand[2 * si] = i0;
    ycand[2 * si + 1] = min(i0 + 1, H - 1);

    float sx = rx1 + ((float)bj + ((float)si + 0.5f) * 0.5f) * bw;
    sx = fminf(fmaxf(sx, 0.0f), (float)(W - 1));
    float fx = floorf(sx);
    wx[si] = sx - fx;
    int j0 = (int)fx;
    xcand[2 * si] = j0;
    xcand[2 * si + 1] = min(j0 + 1, W - 1);
  }
}

// ---- fused prep: features -> bf16 map AND weights -> bf16 [49][9][8][224] ----
constexpr long long FTOT = (long long)H * W * (KW / 4);      // ushort4 units
constexpr int FBLK = (int)((FTOT + 255) / 256);
constexpr int WTOT = 49 * 9 * 8 * (KW / 4);
constexpr int WBLK = (WTOT + 255) / 256;

__global__ __launch_bounds__(256) void prep_kernel(
    const float* __restrict__ feat, const float* __restrict__ Woff,
    unsigned short* __restrict__ fbf, unsigned short* __restrict__ wbf)
{
  const int b = blockIdx.x;
  if (b < FBLK) {
    const long long u = (long long)b * 256 + threadIdx.x;
    if (u >= FTOT) return;
    const int k4 = (int)(u % (KW / 4));
    const long long pix = u / (KW / 4);
    const int k = k4 * 4;
    ushort4 v = make_ushort4(0, 0, 0, 0);
    const float* src = feat + pix * C;
#pragma unroll
    for (int j = 0; j < 4; ++j)
      if (k + j < C) ((unsigned short*)&v)[j] = f2bf(src[k + j]);
    *reinterpret_cast<ushort4*>(fbf + pix * KW + k) = v;
  } else {
    const int u = (b - FBLK) * 256 + threadIdx.x;
    if (u >= WTOT) return;
    const int k4 = u % (KW / 4);
    const int n  = (u / (KW / 4)) % 8;
    const int p  = (u / (KW / 4 * 8)) % 9;
    const int g  = u / (KW / 4 * 8 * 9);
    const int k  = k4 * 4;
    ushort4 v = make_ushort4(0, 0, 0, 0);
    const int o = g * 8 + n;
#pragma unroll
    for (int j = 0; j < 4; ++j)
      if (k + j < C)
        ((unsigned short*)&v)[j] = f2bf(Woff[(size_t)(p * C + k + j) * CO + o]);
    *reinterpret_cast<ushort4*>(wbf + ((size_t)(g * 9 + p) * 8 + n) * KW + k) = v;
  }
}

// ---- main: one wave per (roi, bin); no LDS, no barriers; full unroll ----
__global__ __launch_bounds__(256, 4) void psroi_wave_kernel(
    const float* __restrict__ feat, const float* __restrict__ rois,
    const unsigned short* __restrict__ fbf,
    const unsigned short* __restrict__ wbf,
    const float* __restrict__ boff, float* __restrict__ out)
{
  // bijective XCD swizzle over 6272 blocks (6272 % 8 == 0)
  const int bid = blockIdx.x;
  const int wid = (bid & 7) * (49 * NROI / 4 / 8) + (bid >> 3);
  const int wv = threadIdx.x >> 6;
  const int lane = threadIdx.x & 63;
  const int site = wid * 4 + wv;            // 0..25087
  const int n = site / 49, g = site % 49;
  const int bi = g / KK, bj = g % KK;
  const int m_lane = lane & 15;
  const int k_hi = lane >> 4;

  int yc4[4], xc4[4];
  float wy2[2], wx2[2];
  roi_geom(rois, n, bi, bj, yc4, xc4, wy2, wx2);

  // this lane's corner for A rows (corner id = m_lane = ycidx*4 + xcidx)
  const int ycc = yc4[m_lane >> 2];
  const int xcc = xc4[m_lane & 3];

  f32x4 acc = {0.f, 0.f, 0.f, 0.f};
  const unsigned short* wg = wbf + (size_t)g * 9 * 8 * KW;
  const bool bok = (m_lane < 8);

  // ---- conv: all 9 taps x 7 ks fully unrolled; compiler hoists loads
  // (128-VGPR budget from __launch_bounds__(256,4)) ----
#pragma unroll
  for (int dy = -1; dy <= 1; ++dy) {
    const int ys = ycc + dy;
    const bool yok = (ys >= 0) && (ys < H);
#pragma unroll
    for (int t = 0; t < 3; ++t) {
      const int xs = xcc + t - 1;
      const bool aok = yok && (xs >= 0) && (xs < W);
      const unsigned short* ar = fbf + (size_t)(ys * W + xs) * KW + k_hi * 8;
      const int p = (dy + 1) * 3 + t;
      const unsigned short* br = wg + ((size_t)p * 8 + m_lane) * KW + k_hi * 8;
#pragma unroll
      for (int ks = 0; ks < 7; ++ks) {
        bf16x8 a = (bf16x8)(short)0;
        if (aok) a = *reinterpret_cast<const bf16x8*>(ar + ks * 32);
        bf16x8 b = (bf16x8)(short)0;
        if (bok) b = *reinterpret_cast<const bf16x8*>(br + ks * 32);
        acc = __builtin_amdgcn_mfma_f32_16x16x32_bf16(a, b, acc, 0, 0, 0);
      }
    }
  }

  // ---- C redistribution via shuffles (no LDS, no barrier) ----
  const int ct = lane >> 2;                 // target corner 0..15
  const int d  = lane & 3;
  const int srcy = ((ct >> 2) << 4) + 2 * d;
  const int srcx = srcy + 1;
  const float ty0 = __shfl(acc[0], srcy), ty1 = __shfl(acc[1], srcy);
  const float ty2 = __shfl(acc[2], srcy), ty3 = __shfl(acc[3], srcy);
  const float tx0 = __shfl(acc[0], srcx), tx1 = __shfl(acc[1], srcx);
  const float tx2 = __shfl(acc[2], srcx), tx3 = __shfl(acc[3], srcx);
  const int rr = ct & 3;
  float offy = (rr == 0) ? ty0 : (rr == 1) ? ty1 : (rr == 2) ? ty2 : ty3;
  float offx = (rr == 0) ? tx0 : (rr == 1) ? tx1 : (rr == 2) ? tx2 : tx3;

  // ---- deformable bilinear fetch (fp32 features) + PS-ROI combine ----
  const int c = g * DIM + d;
  offy += boff[2 * c];
  offx += boff[2 * c + 1];
  const int yc = yc4[ct >> 2];
  const int xc = xc4[ct & 3];

  float yy = fminf(fmaxf((float)yc + offy, 0.0f), (float)(H - 1));
  float xx = fminf(fmaxf((float)xc + offx, 0.0f), (float)(W - 1));
  const float fy = floorf(yy), fx = floorf(xx);
  const float ay = yy - fy, ax = xx - fx;
  const int iy0 = (int)fy, ix0 = (int)fx;
  const int iy1 = min(iy0 + 1, H - 1), ix1 = min(ix0 + 1, W - 1);
  const float v00 = feat[(size_t)(iy0 * W + ix0) * C + c];
  const float v01 = feat[(size_t)(iy0 * W + ix1) * C + c];
  const float v10 = feat[(size_t)(iy1 * W + ix0) * C + c];
  const float v11 = feat[(size_t)(iy1 * W + ix1) * C + c];
  const float top = v00 + (v01 - v00) * ax;
  const float bot = v10 + (v11 - v10) * ax;
  const float om = top + (bot - top) * ay;

  const int yci = ct >> 2, xci = ct & 3;
  const int si = yci >> 1, a = yci & 1;
  const int sj = xci >> 1, b = xci & 1;
  const float cy = a ? wy2[si] : 1.0f - wy2[si];
  const float cx = b ? wx2[sj] : 1.0f - wx2[sj];
  float v = 0.25f * cy * cx * om;

  v += __shfl_xor(v, 4);
  v += __shfl_xor(v, 8);
  v += __shfl_xor(v, 16);
  v += __shfl_xor(v, 32);

  if (lane < 4)
    out[(size_t)n * (KK * KK * DIM) + g * DIM + lane] = v;
}

// ---- fallback (ws too small): round-6 union kernel, fp32 inputs ----
__global__ __launch_bounds__(256) void psroi_union_kernel(
    const float* __restrict__ feat, const float* __restrict__ rois,
    const float* __restrict__ Woff, const float* __restrict__ boff,
    float* __restrict__ out)
{
  const int bid = blockIdx.x;
  const int wid = (bid & 7) * (49 * NROI / 8) + (bid >> 3);
  const int g = wid % 49;
  const int n = wid / 49;
  const int bi = g / KK, bj = g % KK;
  const int tid = threadIdx.x;
  const int lane = tid & 63;
  const int wv = tid >> 6;
  const int m_lane = lane & 15;
  const int k_hi = lane >> 4;

  __shared__ short Abuf[64 * KP];
  __shared__ float Cbuf[4 * 16 * 9];

  for (int i = tid; i < 64 * (KP - C); i += 256) {
    const int row = i / (KP - C), col = C + i % (KP - C);
    Abuf[row * KP + col] = 0;
  }

  int yc4[4], xc4[4];
  float wy2[2], wx2[2];
  roi_geom(rois, n, bi, bj, yc4, xc4, wy2, wx2);

  {
    const int pos = tid >> 2;
    const int yi = pos >> 3, xi = pos & 7;
    const int yrow = (yi < 4) ? (yc4[0] + yi - 1) : (yc4[2] + yi - 5);
    const int xcol = (xi < 4) ? (xc4[0] + xi - 1) : (xc4[2] + xi - 5);
    const bool valid = (yrow >= 0) && (yrow < H) && (xcol >= 0) && (xcol < W);
    const float* frow = feat + (size_t)(yrow * W + xcol) * C;
    short* arow = &Abuf[pos * KP];
    const int l = tid & 3;
#pragma unroll
    for (int k = 0; k <= 12; ++k) {
      const int c = l + 4 * k;
      if (c < 49) {
        ushort4 v = make_ushort4(0, 0, 0, 0);
        if (valid) {
          const float4 f4 = *reinterpret_cast<const float4*>(frow + 4 * c);
          v.x = f2bf(f4.x); v.y = f2bf(f4.y);
          v.z = f2bf(f4.z); v.w = f2bf(f4.w);
        }
        *reinterpret_cast<ushort4*>(arow + 4 * c) = v;
      }
    }
  }
  __syncthreads();

  const int i0 = m_lane >> 2, j0 = m_lane & 3;
  const int dyA = yc4[1] - yc4[0], dyB = yc4[3] - yc4[2];
  const int dxA = xc4[1] - xc4[0], dxB = xc4[3] - xc4[2];
  int ybase = (i0 & 2) ? 5 : 1;
  ybase += (i0 & 1) ? ((i0 & 2) ? dyB : dyA) : 0;
  int xbase = (j0 & 2) ? 5 : 1;
  xbase += (j0 & 1) ? ((j0 & 2) ? dxB : dxA) : 0;

  f32x4 acc = {0.f, 0.f, 0.f, 0.f};

#pragma unroll 1
  for (int p = wv; p < 9; p += 4) {
    bf16x8 bfr[7];
#pragma unroll
    for (int ks = 0; ks < 7; ++ks) bfr[ks] = (bf16x8)(short)0;
    if (m_lane < 8) {
#pragma unroll
      for (int ks = 0; ks < 7; ++ks) {
        bf16x8 b = (bf16x8)(short)0;
#pragma unroll
        for (int j = 0; j < 8; ++j) {
          const int k = ks * 32 + k_hi * 8 + j;
          if (k < C)
            b[j] = (short)f2bf(Woff[(size_t)(p * C + k) * CO + g * 8 + m_lane]);
        }
        bfr[ks] = b;
      }
    }
    const int row = (ybase + p / 3 - 1) * 8 + (xbase + p % 3 - 1);
    const short* arow = &Abuf[row * KP];
#pragma unroll
    for (int ks = 0; ks < 7; ++ks) {
      const bf16x8 a = *reinterpret_cast<const bf16x8*>(arow + ks * 32 + k_hi * 8);
      acc = __builtin_amdgcn_mfma_f32_16x16x32_bf16(a, bfr[ks], acc, 0, 0, 0);
    }
  }

  if (m_lane < 8) {
#pragma unroll
    for (int r = 0; r < 4; ++r)
      Cbuf[(wv * 16 + k_hi * 4 + r) * 9 + m_lane] = acc[r];
  }
  __syncthreads();

  if (tid < 64) {
    const int corner = tid >> 2;
    const int d = tid & 3;
    const int yc = yc4[corner >> 2];
    const int xc = xc4[corner & 3];
    const int c = g * DIM + d;

    float offy = boff[2 * c], offx = boff[2 * c + 1];
#pragma unroll
    for (int w = 0; w < 4; ++w) {
      offy += Cbuf[(w * 16 + corner) * 9 + 2 * d];
      offx += Cbuf[(w * 16 + corner) * 9 + 2 * d + 1];
    }

    float yy = fminf(fmaxf((float)yc + offy, 0.0f), (float)(H - 1));
    float xx = fminf(fmaxf((float)xc + offx, 0.0f), (float)(W - 1));
    const float fy = floorf(yy), fx = floorf(xx);
    const float ay = yy - fy, ax = xx - fx;
    const int iy0 = (int)fy, ix0 = (int)fx;
    const int iy1 = min(iy0 + 1, H - 1), ix1 = min(ix0 + 1, W - 1);
    const float v00 = feat[(size_t)(iy0 * W + ix0) * C + c];
    const float v01 = feat[(size_t)(iy0 * W + ix1) * C + c];
    const float v10 = feat[(size_t)(iy1 * W + ix0) * C + c];
    const float v11 = feat[(size_t)(iy1 * W + ix1) * C + c];
    const float top = v00 + (v01 - v00) * ax;
    const float bot = v10 + (v11 - v10) * ax;
    const float om = top + (bot - top) * ay;

    const int yci = corner >> 2, xci = corner & 3;
    const int si = yci >> 1, a = yci & 1;
    const int sj = xci >> 1, b = xci & 1;
    const float cy = a ? wy2[si] : 1.0f - wy2[si];
    const float cx = b ? wx2[sj] : 1.0f - wx2[sj];
    float v = 0.25f * cy * cx * om;

    v += __shfl_xor(v, 4);
    v += __shfl_xor(v, 8);
    v += __shfl_xor(v, 16);
    v += __shfl_xor(v, 32);

    if (tid < 4)
      out[(size_t)n * (KK * KK * DIM) + g * DIM + tid] = v;
  }
}

extern "C" void kernel_launch(void* const* d_in, const int* in_sizes, int n_in,
                              void* d_out, int out_size, void* d_ws, size_t ws_size,
                              hipStream_t stream) {
  const float* feat = (const float*)d_in[0];
  const float* rois = (const float*)d_in[1];
  const float* Woff = (const float*)d_in[2];
  const float* boff = (const float*)d_in[3];
  float* out = (float*)d_out;

  if (ws_size >= WS_NEED) {
    unsigned short* fbf = (unsigned short*)d_ws;
    unsigned short* wbf = fbf + F_ELEMS;
    prep_kernel<<<dim3(FBLK + WBLK), dim3(256), 0, stream>>>(feat, Woff, fbf, wbf);
    psroi_wave_kernel<<<dim3(49 * NROI / 4), dim3(256), 0, stream>>>(
        feat, rois, fbf, wbf, boff, out);
  } else {
    psroi_union_kernel<<<dim3(49 * NROI), dim3(256), 0, stream>>>(
        feat, rois, Woff, boff, out);
  }
}

// Round 14
// 227.327 us; speedup vs baseline: 1.1063x; 1.0529x over previous
//
#include <hip/hip_runtime.h>

// PsRoiOffset, round 13: wave-per-site with BRANCH-FREE loads.
// R12's null result: VGPR stayed 28 because every load was guarded by a
// divergent if(aok)/if(bok) -> compiler could not speculate/hoist ->
// ~4 loads in flight -> vmcnt-serialized. This round:
//   - A-loads: clamped (always-valid) address, unconditional load,
//     zero applied via data select (v_cndmask), no branch.
//   - B-loads: unmasked -- lanes m_lane>=8 load a duplicate row (m&7);
//     their garbage lands in C columns 8..15 which are never read.
// Straight-line unrolled body + __launch_bounds__(256,4) = 128-VGPR
// budget -> scheduler can batch loads.
//
// features (1,200,304,196) f32, rois (512,4) f32,
// W_off (3,3,196,392) f32, b_off (392) f32, out (512,7,7,4) f32.
// ws: bf16 map [H][W][224] + bf16 weights [49][9][8][224].

constexpr int H = 200, W = 304, C = 196, CO = 392;
constexpr int KK = 7, DIM = 4, NROI = 512;
constexpr int KW = 224;
constexpr int KP = 232;                       // fallback LDS A row stride
constexpr size_t F_ELEMS = (size_t)H * W * KW;
constexpr size_t W_ELEMS = (size_t)49 * 9 * 8 * KW;
constexpr size_t WS_NEED = (F_ELEMS + W_ELEMS) * 2;   // ~28.8 MB

typedef __attribute__((ext_vector_type(8))) short bf16x8;
typedef __attribute__((ext_vector_type(4))) float f32x4;

static __device__ inline unsigned short f2bf(float x) {
  unsigned int u = __float_as_uint(x);
  return (unsigned short)((u + 0x7FFFu + ((u >> 16) & 1u)) >> 16);
}

static __device__ inline void roi_geom(const float* __restrict__ rois, int n,
                                       int bi, int bj,
                                       int* ycand, int* xcand,
                                       float* wy, float* wx) {
  const float rx1 = rois[n * 4 + 0] * 0.25f;
  const float ry1 = rois[n * 4 + 1] * 0.25f;
  const float rx2 = rois[n * 4 + 2] * 0.25f;
  const float ry2 = rois[n * 4 + 3] * 0.25f;
  const float bh = (ry2 - ry1) * (1.0f / 7.0f);
  const float bw = (rx2 - rx1) * (1.0f / 7.0f);
#pragma unroll
  for (int si = 0; si < 2; ++si) {
    float sy = ry1 + ((float)bi + ((float)si + 0.5f) * 0.5f) * bh;
    sy = fminf(fmaxf(sy, 0.0f), (float)(H - 1));
    float fy = floorf(sy);
    wy[si] = sy - fy;
    int i0 = (int)fy;
    ycand[2 * si] = i0;
    ycand[2 * si + 1] = min(i0 + 1, H - 1);

    float sx = rx1 + ((float)bj + ((float)si + 0.5f) * 0.5f) * bw;
    sx = fminf(fmaxf(sx, 0.0f), (float)(W - 1));
    float fx = floorf(sx);
    wx[si] = sx - fx;
    int j0 = (int)fx;
    xcand[2 * si] = j0;
    xcand[2 * si + 1] = min(j0 + 1, W - 1);
  }
}

// ---- fused prep: features -> bf16 map AND weights -> bf16 [49][9][8][224] ----
constexpr long long FTOT = (long long)H * W * (KW / 4);
constexpr int FBLK = (int)((FTOT + 255) / 256);
constexpr int WTOT = 49 * 9 * 8 * (KW / 4);
constexpr int WBLK = (WTOT + 255) / 256;

__global__ __launch_bounds__(256) void prep_kernel(
    const float* __restrict__ feat, const float* __restrict__ Woff,
    unsigned short* __restrict__ fbf, unsigned short* __restrict__ wbf)
{
  const int b = blockIdx.x;
  if (b < FBLK) {
    const long long u = (long long)b * 256 + threadIdx.x;
    if (u >= FTOT) return;
    const int k4 = (int)(u % (KW / 4));
    const long long pix = u / (KW / 4);
    const int k = k4 * 4;
    ushort4 v = make_ushort4(0, 0, 0, 0);
    const float* src = feat + pix * C;
#pragma unroll
    for (int j = 0; j < 4; ++j)
      if (k + j < C) ((unsigned short*)&v)[j] = f2bf(src[k + j]);
    *reinterpret_cast<ushort4*>(fbf + pix * KW + k) = v;
  } else {
    const int u = (b - FBLK) * 256 + threadIdx.x;
    if (u >= WTOT) return;
    const int k4 = u % (KW / 4);
    const int n  = (u / (KW / 4)) % 8;
    const int p  = (u / (KW / 4 * 8)) % 9;
    const int g  = u / (KW / 4 * 8 * 9);
    const int k  = k4 * 4;
    ushort4 v = make_ushort4(0, 0, 0, 0);
    const int o = g * 8 + n;
#pragma unroll
    for (int j = 0; j < 4; ++j)
      if (k + j < C)
        ((unsigned short*)&v)[j] = f2bf(Woff[(size_t)(p * C + k + j) * CO + o]);
    *reinterpret_cast<ushort4*>(wbf + ((size_t)(g * 9 + p) * 8 + n) * KW + k) = v;
  }
}

// ---- main: one wave per (roi, bin); branch-free loads ----
__global__ __launch_bounds__(256, 4) void psroi_wave_kernel(
    const float* __restrict__ feat, const float* __restrict__ rois,
    const unsigned short* __restrict__ fbf,
    const unsigned short* __restrict__ wbf,
    const float* __restrict__ boff, float* __restrict__ out)
{
  // bijective XCD swizzle over 6272 blocks (6272 % 8 == 0)
  const int bid = blockIdx.x;
  const int wid = (bid & 7) * (49 * NROI / 4 / 8) + (bid >> 3);
  const int wv = threadIdx.x >> 6;
  const int lane = threadIdx.x & 63;
  const int site = wid * 4 + wv;            // 0..25087
  const int n = site / 49, g = site % 49;
  const int bi = g / KK, bj = g % KK;
  const int m_lane = lane & 15;
  const int k_hi = lane >> 4;

  int yc4[4], xc4[4];
  float wy2[2], wx2[2];
  roi_geom(rois, n, bi, bj, yc4, xc4, wy2, wx2);

  // this lane's corner for A rows (corner id = m_lane = ycidx*4 + xcidx)
  const int ycc = yc4[m_lane >> 2];
  const int xcc = xc4[m_lane & 3];

  f32x4 acc = {0.f, 0.f, 0.f, 0.f};
  // B: no mask -- m_lane>=8 loads duplicate row (m&7); garbage lands in
  // C cols 8..15 which the shuffle epilogue never reads.
  const unsigned short* wg =
      wbf + (size_t)g * 9 * 8 * KW + (size_t)(m_lane & 7) * KW + k_hi * 8;

  // ---- conv: all 9 taps x 7 ks, branch-free (clamped addr + data select)
#pragma unroll
  for (int dy = -1; dy <= 1; ++dy) {
    const int ys = ycc + dy;
    const int ysc = min(max(ys, 0), H - 1);
    const bool yok = (ys >= 0) && (ys < H);
#pragma unroll
    for (int t = 0; t < 3; ++t) {
      const int xs = xcc + t - 1;
      const int xsc = min(max(xs, 0), W - 1);
      const bool aok = yok && (xs >= 0) && (xs < W);
      const unsigned short* ar = fbf + (size_t)(ysc * W + xsc) * KW + k_hi * 8;
      const unsigned short* br = wg + (size_t)((dy + 1) * 3 + t) * 8 * KW;
#pragma unroll
      for (int ks = 0; ks < 7; ++ks) {
        bf16x8 a = *reinterpret_cast<const bf16x8*>(ar + ks * 32);
        a = aok ? a : (bf16x8)(short)0;   // v_cndmask, no branch
        const bf16x8 b = *reinterpret_cast<const bf16x8*>(br + ks * 32);
        acc = __builtin_amdgcn_mfma_f32_16x16x32_bf16(a, b, acc, 0, 0, 0);
      }
    }
  }

  // ---- C redistribution via shuffles (no LDS, no barrier) ----
  const int ct = lane >> 2;                 // target corner 0..15
  const int d  = lane & 3;
  const int srcy = ((ct >> 2) << 4) + 2 * d;
  const int srcx = srcy + 1;
  const float ty0 = __shfl(acc[0], srcy), ty1 = __shfl(acc[1], srcy);
  const float ty2 = __shfl(acc[2], srcy), ty3 = __shfl(acc[3], srcy);
  const float tx0 = __shfl(acc[0], srcx), tx1 = __shfl(acc[1], srcx);
  const float tx2 = __shfl(acc[2], srcx), tx3 = __shfl(acc[3], srcx);
  const int rr = ct & 3;
  float offy = (rr == 0) ? ty0 : (rr == 1) ? ty1 : (rr == 2) ? ty2 : ty3;
  float offx = (rr == 0) ? tx0 : (rr == 1) ? tx1 : (rr == 2) ? tx2 : tx3;

  // ---- deformable bilinear fetch (fp32 features) + PS-ROI combine ----
  const int c = g * DIM + d;
  offy += boff[2 * c];
  offx += boff[2 * c + 1];
  const int yc = yc4[ct >> 2];
  const int xc = xc4[ct & 3];

  float yy = fminf(fmaxf((float)yc + offy, 0.0f), (float)(H - 1));
  float xx = fminf(fmaxf((float)xc + offx, 0.0f), (float)(W - 1));
  const float fy = floorf(yy), fx = floorf(xx);
  const float ay = yy - fy, ax = xx - fx;
  const int iy0 = (int)fy, ix0 = (int)fx;
  const int iy1 = min(iy0 + 1, H - 1), ix1 = min(ix0 + 1, W - 1);
  const float v00 = feat[(size_t)(iy0 * W + ix0) * C + c];
  const float v01 = feat[(size_t)(iy0 * W + ix1) * C + c];
  const float v10 = feat[(size_t)(iy1 * W + ix0) * C + c];
  const float v11 = feat[(size_t)(iy1 * W + ix1) * C + c];
  const float top = v00 + (v01 - v00) * ax;
  const float bot = v10 + (v11 - v10) * ax;
  const float om = top + (bot - top) * ay;

  const int yci = ct >> 2, xci = ct & 3;
  const int si = yci >> 1, a = yci & 1;
  const int sj = xci >> 1, b = xci & 1;
  const float cy = a ? wy2[si] : 1.0f - wy2[si];
  const float cx = b ? wx2[sj] : 1.0f - wx2[sj];
  float v = 0.25f * cy * cx * om;

  v += __shfl_xor(v, 4);
  v += __shfl_xor(v, 8);
  v += __shfl_xor(v, 16);
  v += __shfl_xor(v, 32);

  if (lane < 4)
    out[(size_t)n * (KK * KK * DIM) + g * DIM + lane] = v;
}

// ---- fallback (ws too small): round-6 union kernel, fp32 inputs ----
__global__ __launch_bounds__(256) void psroi_union_kernel(
    const float* __restrict__ feat, const float* __restrict__ rois,
    const float* __restrict__ Woff, const float* __restrict__ boff,
    float* __restrict__ out)
{
  const int bid = blockIdx.x;
  const int wid = (bid & 7) * (49 * NROI / 8) + (bid >> 3);
  const int g = wid % 49;
  const int n = wid / 49;
  const int bi = g / KK, bj = g % KK;
  const int tid = threadIdx.x;
  const int lane = tid & 63;
  const int wv = tid >> 6;
  const int m_lane = lane & 15;
  const int k_hi = lane >> 4;

  __shared__ short Abuf[64 * KP];
  __shared__ float Cbuf[4 * 16 * 9];

  for (int i = tid; i < 64 * (KP - C); i += 256) {
    const int row = i / (KP - C), col = C + i % (KP - C);
    Abuf[row * KP + col] = 0;
  }

  int yc4[4], xc4[4];
  float wy2[2], wx2[2];
  roi_geom(rois, n, bi, bj, yc4, xc4, wy2, wx2);

  {
    const int pos = tid >> 2;
    const int yi = pos >> 3, xi = pos & 7;
    const int yrow = (yi < 4) ? (yc4[0] + yi - 1) : (yc4[2] + yi - 5);
    const int xcol = (xi < 4) ? (xc4[0] + xi - 1) : (xc4[2] + xi - 5);
    const bool valid = (yrow >= 0) && (yrow < H) && (xcol >= 0) && (xcol < W);
    const float* frow = feat + (size_t)(yrow * W + xcol) * C;
    short* arow = &Abuf[pos * KP];
    const int l = tid & 3;
#pragma unroll
    for (int k = 0; k <= 12; ++k) {
      const int c = l + 4 * k;
      if (c < 49) {
        ushort4 v = make_ushort4(0, 0, 0, 0);
        if (valid) {
          const float4 f4 = *reinterpret_cast<const float4*>(frow + 4 * c);
          v.x = f2bf(f4.x); v.y = f2bf(f4.y);
          v.z = f2bf(f4.z); v.w = f2bf(f4.w);
        }
        *reinterpret_cast<ushort4*>(arow + 4 * c) = v;
      }
    }
  }
  __syncthreads();

  const int i0 = m_lane >> 2, j0 = m_lane & 3;
  const int dyA = yc4[1] - yc4[0], dyB = yc4[3] - yc4[2];
  const int dxA = xc4[1] - xc4[0], dxB = xc4[3] - xc4[2];
  int ybase = (i0 & 2) ? 5 : 1;
  ybase += (i0 & 1) ? ((i0 & 2) ? dyB : dyA) : 0;
  int xbase = (j0 & 2) ? 5 : 1;
  xbase += (j0 & 1) ? ((j0 & 2) ? dxB : dxA) : 0;

  f32x4 acc = {0.f, 0.f, 0.f, 0.f};

#pragma unroll 1
  for (int p = wv; p < 9; p += 4) {
    bf16x8 bfr[7];
#pragma unroll
    for (int ks = 0; ks < 7; ++ks) bfr[ks] = (bf16x8)(short)0;
    if (m_lane < 8) {
#pragma unroll
      for (int ks = 0; ks < 7; ++ks) {
        bf16x8 b = (bf16x8)(short)0;
#pragma unroll
        for (int j = 0; j < 8; ++j) {
          const int k = ks * 32 + k_hi * 8 + j;
          if (k < C)
            b[j] = (short)f2bf(Woff[(size_t)(p * C + k) * CO + g * 8 + m_lane]);
        }
        bfr[ks] = b;
      }
    }
    const int row = (ybase + p / 3 - 1) * 8 + (xbase + p % 3 - 1);
    const short* arow = &Abuf[row * KP];
#pragma unroll
    for (int ks = 0; ks < 7; ++ks) {
      const bf16x8 a = *reinterpret_cast<const bf16x8*>(arow + ks * 32 + k_hi * 8);
      acc = __builtin_amdgcn_mfma_f32_16x16x32_bf16(a, bfr[ks], acc, 0, 0, 0);
    }
  }

  if (m_lane < 8) {
#pragma unroll
    for (int r = 0; r < 4; ++r)
      Cbuf[(wv * 16 + k_hi * 4 + r) * 9 + m_lane] = acc[r];
  }
  __syncthreads();

  if (tid < 64) {
    const int corner = tid >> 2;
    const int d = tid & 3;
    const int yc = yc4[corner >> 2];
    const int xc = xc4[corner & 3];
    const int c = g * DIM + d;

    float offy = boff[2 * c], offx = boff[2 * c + 1];
#pragma unroll
    for (int w = 0; w < 4; ++w) {
      offy += Cbuf[(w * 16 + corner) * 9 + 2 * d];
      offx += Cbuf[(w * 16 + corner) * 9 + 2 * d + 1];
    }

    float yy = fminf(fmaxf((float)yc + offy, 0.0f), (float)(H - 1));
    float xx = fminf(fmaxf((float)xc + offx, 0.0f), (float)(W - 1));
    const float fy = floorf(yy), fx = floorf(xx);
    const float ay = yy - fy, ax = xx - fx;
    const int iy0 = (int)fy, ix0 = (int)fx;
    const int iy1 = min(iy0 + 1, H - 1), ix1 = min(ix0 + 1, W - 1);
    const float v00 = feat[(size_t)(iy0 * W + ix0) * C + c];
    const float v01 = feat[(size_t)(iy0 * W + ix1) * C + c];
    const float v10 = feat[(size_t)(iy1 * W + ix0) * C + c];
    const float v11 = feat[(size_t)(iy1 * W + ix1) * C + c];
    const float top = v00 + (v01 - v00) * ax;
    const float bot = v10 + (v11 - v10) * ax;
    const float om = top + (bot - top) * ay;

    const int yci = corner >> 2, xci = corner & 3;
    const int si = yci >> 1, a = yci & 1;
    const int sj = xci >> 1, b = xci & 1;
    const float cy = a ? wy2[si] : 1.0f - wy2[si];
    const float cx = b ? wx2[sj] : 1.0f - wx2[sj];
    float v = 0.25f * cy * cx * om;

    v += __shfl_xor(v, 4);
    v += __shfl_xor(v, 8);
    v += __shfl_xor(v, 16);
    v += __shfl_xor(v, 32);

    if (tid < 4)
      out[(size_t)n * (KK * KK * DIM) + g * DIM + tid] = v;
  }
}

extern "C" void kernel_launch(void* const* d_in, const int* in_sizes, int n_in,
                              void* d_out, int out_size, void* d_ws, size_t ws_size,
                              hipStream_t stream) {
  const float* feat = (const float*)d_in[0];
  const float* rois = (const float*)d_in[1];
  const float* Woff = (const float*)d_in[2];
  const float* boff = (const float*)d_in[3];
  float* out = (float*)d_out;

  if (ws_size >= WS_NEED) {
    unsigned short* fbf = (unsigned short*)d_ws;
    unsigned short* wbf = fbf + F_ELEMS;
    prep_kernel<<<dim3(FBLK + WBLK), dim3(256), 0, stream>>>(feat, Woff, fbf, wbf);
    psroi_wave_kernel<<<dim3(49 * NROI / 4), dim3(256), 0, stream>>>(
        feat, rois, fbf, wbf, boff, out);
  } else {
    psroi_union_kernel<<<dim3(49 * NROI), dim3(256), 0, stream>>>(
        feat, rois, Woff, boff, out);
  }
}